// Round 3
// baseline (1186.886 us; speedup 1.0000x reference)
//
#include <hip/hip_runtime.h>
#include <math.h>

// 2-layer GCN, fp32: out = sigmoid(gcn(relu(gcn(x, W0, b0)), W1, b1))
// NOTE: harness delivers integer inputs as int32 (edge_index is const int*).
// Fusion: agg(x @ W) == agg(x) @ W (segment-sum linear) -> layer 1 aggregates
// raw 64-feat x, then a single fused kernel does (+self-loop) @W0 +b0, relu,
// @W1 with the 128-wide hidden kept in LDS, writing hw1 IN-PLACE over agg(x).
// Layer-2 aggregation accumulates straight into d_out; final pass adds
// self-loop term + b1 and applies sigmoid in place.
// Workspace: N floats (dis) + N*64 floats (agg/hw1 buffer) = 26 MB.

#define FIN 64
#define FHID 128
#define FOUT 64
#define ROWS_PER_BLOCK 32

__global__ void k_deg_init(float* __restrict__ dis, int n) {
    int i = blockIdx.x * blockDim.x + threadIdx.x;
    if (i < n) dis[i] = 1.0f;   // self-loop contributes 1 to every degree
}

__global__ void k_deg_accum(const int* __restrict__ dst,
                            float* __restrict__ deg, int e) {
    int i = blockIdx.x * blockDim.x + threadIdx.x;
    if (i < e) atomicAdd(&deg[dst[i]], 1.0f);
}

__global__ void k_rsqrt(float* __restrict__ dis, int n) {
    int i = blockIdx.x * blockDim.x + threadIdx.x;
    if (i < n) dis[i] = rsqrtf(dis[i]);   // deg >= 1 always
}

// One 64-lane wave per edge; lane = feature index.
// agg[dst][f] += feat[src][f] * dis[src]*dis[dst]
__global__ void k_edge_agg64(const int* __restrict__ src,
                             const int* __restrict__ dst,
                             const float* __restrict__ dis,
                             const float* __restrict__ feat,
                             float* __restrict__ agg, int e) {
    long long gid = (long long)blockIdx.x * blockDim.x + threadIdx.x;
    int edge = (int)(gid >> 6);
    int f    = (int)(gid & 63);
    if (edge >= e) return;
    int s = src[edge];
    int d = dst[edge];
    float nrm = dis[s] * dis[d];
    float v = feat[(size_t)s * 64 + f] * nrm;
    atomicAdd(&agg[(size_t)d * 64 + f], v);
}

// Fused MLP: reads agg_io (= agg(x)) + x, computes
//   hidden = relu((agg + dis^2 * x) @ W0 + b0)   [128 wide, kept in LDS]
//   hw1    = hidden @ W1                          [64 wide]
// and writes hw1 IN-PLACE into agg_io. Each block owns its rows; reads of a
// row complete (via __syncthreads) before any write to it.
__global__ __launch_bounds__(256) void k_fused_mlp(
        const float* __restrict__ x,
        float* agg_io,                     // aliased read+write (no restrict)
        const float* __restrict__ dis,
        const float* __restrict__ W0,      // [64][128]
        const float* __restrict__ b0,      // [128]
        const float* __restrict__ W1,      // [128][64]
        int n) {
    __shared__ float w0s[FIN * FHID];      // 32 KB
    __shared__ float xs[4][FIN];           // 1 KB
    __shared__ float hs[4][FHID];          // 2 KB
    int t = threadIdx.x;
    for (int i = t; i < FIN * FHID; i += 256) w0s[i] = W0[i];

    int cA = t & 127, rsA = t >> 7;        // stage A: col 0..127, row-slot 0..1
    int cB = t & 63,  rB  = t >> 6;        // stage B: col 0..63,  row 0..3
    float b0c = b0[cA];

    int row0 = blockIdx.x * ROWS_PER_BLOCK;
    for (int it = 0; it < ROWS_PER_BLOCK / 4; ++it) {
        int rbase = row0 + it * 4;
        __syncthreads();                   // xs/hs reuse; w0s ready (1st iter)
        {   // load pre-activation input: agg + dis^2 * x   (4 rows x 64)
            int rr = t >> 6, k = t & 63;
            int grow = rbase + rr;
            float v = 0.0f;
            if (grow < n) {
                float di = dis[grow];
                size_t o = (size_t)grow * FIN + k;
                v = agg_io[o] + di * di * x[o];
            }
            xs[rr][k] = v;
        }
        __syncthreads();
        // stage A: hidden for rows rsA and rsA+2, column cA
        float a0 = b0c, a1 = b0c;
        #pragma unroll
        for (int k = 0; k < FIN; ++k) {
            float w = w0s[k * FHID + cA];
            a0 = fmaf(xs[rsA][k],     w, a0);
            a1 = fmaf(xs[rsA + 2][k], w, a1);
        }
        hs[rsA][cA]     = fmaxf(a0, 0.0f);
        hs[rsA + 2][cA] = fmaxf(a1, 0.0f);
        __syncthreads();
        // stage B: hw1 row rB, column cB (W1 streamed via L1/L2, 32 KB total)
        float acc = 0.0f;
        #pragma unroll
        for (int k = 0; k < FHID; ++k)
            acc = fmaf(hs[rB][k], W1[k * FOUT + cB], acc);
        int grow = rbase + rB;
        if (grow < n) agg_io[(size_t)grow * FOUT + cB] = acc;  // in-place
    }
}

// out = sigmoid( out(=agg2) + dis^2 * hw1 + b1 )   in place
__global__ void k_final(float* __restrict__ out,
                        const float* __restrict__ hw1,
                        const float* __restrict__ dis,
                        const float* __restrict__ b1, int n) {
    int i = blockIdx.x * blockDim.x + threadIdx.x;
    if (i >= n * FOUT) return;
    int node = i >> 6, f = i & 63;
    float di = dis[node];
    float v = out[i] + di * di * hw1[i] + b1[f];
    out[i] = 1.0f / (1.0f + expf(-v));
}

extern "C" void kernel_launch(void* const* d_in, const int* in_sizes, int n_in,
                              void* d_out, int out_size, void* d_ws, size_t ws_size,
                              hipStream_t stream) {
    const float* x   = (const float*)d_in[0];
    const int*   ei  = (const int*)d_in[1];   // int32 [2, E] (harness contract)
    const float* W0  = (const float*)d_in[2];
    const float* b0  = (const float*)d_in[3];
    const float* W1  = (const float*)d_in[4];
    const float* b1  = (const float*)d_in[5];
    float*       out = (float*)d_out;

    const int n = in_sizes[0] / FIN;        // 100000
    const int e = in_sizes[1] / 2;          // 1600000
    const int* src = ei;                    // edge_index[0]
    const int* dst = ei + e;                // edge_index[1]

    // workspace: dis [N] + buf [N*64]  = 26 MB
    size_t need = ((size_t)n + (size_t)n * FIN) * sizeof(float);
    if (ws_size < need) return;             // degrade to absmax-fail, not fault
    float* dis = (float*)d_ws;
    float* buf = dis + n;                   // agg(x), then hw1 (in place)

    hipMemsetAsync(buf, 0, (size_t)n * FIN  * sizeof(float), stream);
    hipMemsetAsync(out, 0, (size_t)n * FOUT * sizeof(float), stream);

    // dis = rsqrt(1 + indegree)
    k_deg_init<<<(n + 255) / 256, 256, 0, stream>>>(dis, n);
    k_deg_accum<<<(e + 255) / 256, 256, 0, stream>>>(dst, dis, e);
    k_rsqrt<<<(n + 255) / 256, 256, 0, stream>>>(dis, n);

    // layer 1 aggregation: buf = segment_sum(norm * x[src]) over dst
    {
        long long threads = (long long)e * 64;
        int blocks = (int)((threads + 255) / 256);
        k_edge_agg64<<<blocks, 256, 0, stream>>>(src, dst, dis, x, buf, e);
    }

    // fused: buf = relu((buf + dis^2*x) @ W0 + b0) @ W1   (in place)
    k_fused_mlp<<<(n + ROWS_PER_BLOCK - 1) / ROWS_PER_BLOCK, 256, 0, stream>>>(
        x, buf, dis, W0, b0, W1, n);

    // layer 2 aggregation straight into d_out
    {
        long long threads = (long long)e * 64;
        int blocks = (int)((threads + 255) / 256);
        k_edge_agg64<<<blocks, 256, 0, stream>>>(src, dst, dis, buf, out, e);
    }

    // out = sigmoid(out + dis^2 * buf + b1)
    k_final<<<(n * FOUT + 255) / 256, 256, 0, stream>>>(out, buf, dis, b1, n);
}

// Round 4
// 882.020 us; speedup vs baseline: 1.3456x; 1.3456x over previous
//
#include <hip/hip_runtime.h>
#include <math.h>

// 2-layer GCN, fp32: out = sigmoid(gcn(relu(gcn(x, W0, b0)), W1, b1))
// edge_index arrives as int32 (harness integer contract).
// agg(x @ W) == agg(x) @ W -> layer 1 aggregates raw 64-feat x, then one
// register-tiled fused MLP (W0 in LDS, W1 preloaded to regs then LDS) does
//   hw1 = relu((agg + dis^2 x) @ W0 + b0) @ W1    in-place over agg.
// Layer-2 aggregation accumulates into d_out; final adds self-loop + b1,
// applies sigmoid. Workspace: N + N*64 floats = 26 MB.

#define FIN 64
#define FHID 128
#define FOUT 64
#define PR 32   // rows per MLP panel/block

__global__ void k_deg_init(float* __restrict__ dis, int n) {
    int i = blockIdx.x * blockDim.x + threadIdx.x;
    if (i < n) dis[i] = 1.0f;
}

__global__ void k_deg_accum(const int* __restrict__ dst,
                            float* __restrict__ deg, int e) {
    int i = blockIdx.x * blockDim.x + threadIdx.x;
    if (i < e) atomicAdd(&deg[dst[i]], 1.0f);
}

__global__ void k_rsqrt(float* __restrict__ dis, int n) {
    int i = blockIdx.x * blockDim.x + threadIdx.x;
    if (i < n) dis[i] = rsqrtf(dis[i]);
}

// One 64-lane wave per edge; lane = feature. Coalesced 256B gather + 256B
// contiguous atomic scatter.
__global__ void k_edge_agg64(const int* __restrict__ src,
                             const int* __restrict__ dst,
                             const float* __restrict__ dis,
                             const float* __restrict__ feat,
                             float* __restrict__ agg, int e) {
    long long gid = (long long)blockIdx.x * blockDim.x + threadIdx.x;
    int edge = (int)(gid >> 6);
    int f    = (int)(gid & 63);
    if (edge >= e) return;
    int s = src[edge];
    int d = dst[edge];
    float nrm = dis[s] * dis[d];
    float v = feat[(size_t)s * 64 + f] * nrm;
    atomicAdd(&agg[(size_t)d * 64 + f], v);
}

// Register-tiled fused MLP. One 32-row panel per block, 256 threads.
// LDS: wts (32KB, W0 then W1) + xs[32][65] + hs[32][129] = 56.8KB -> 2 blk/CU.
// Stage A: thread tile 4 rows x 4 cols (16 acc); per k: 4 bcast reads + 1
//   float4 (4-way, 1.58x) -> 16 FMA. Stage B: 2 rows x 4 cols; per k: 2 bcast
//   + 1 float4 (2-way free) -> 8 FMA. No global loads in either inner loop.
__global__ __launch_bounds__(256, 2) void k_mlp_v2(
        const float* __restrict__ x,
        float* agg_io,                      // aliased read+write
        const float* __restrict__ dis,
        const float* __restrict__ W0,       // [64][128]
        const float* __restrict__ b0,       // [128]
        const float* __restrict__ W1,       // [128][64]
        int n) {
    __shared__ float wts[FIN * FHID];       // 8192 floats: W0, then W1
    __shared__ float xs[PR][FIN + 1];       // pad 65: bcast reads conflict-free
    __shared__ float hs[PR][FHID + 1];      // pad 129
    int t = threadIdx.x;
    int row0 = blockIdx.x * PR;

    // preload W1 (128x64 = 2048 float4) into 8 float4 regs/thread
    float4 w1r[8];
    #pragma unroll
    for (int i = 0; i < 8; ++i)
        w1r[i] = reinterpret_cast<const float4*>(W1)[t + i * 256];

    // stage W0 into LDS
    #pragma unroll
    for (int i = 0; i < 8; ++i)
        reinterpret_cast<float4*>(wts)[t + i * 256] =
            reinterpret_cast<const float4*>(W0)[t + i * 256];

    // fill xs = agg + dis^2 * x : thread t -> row t>>3, cols (t&7)*8..+7
    {
        int r = t >> 3, k0 = (t & 7) * 8;
        int grow = row0 + r;
        float v[8];
        if (grow < n) {
            float di = dis[grow];
            float d2 = di * di;
            const float4* ap = reinterpret_cast<const float4*>(
                agg_io + (size_t)grow * FIN + k0);
            const float4* xp = reinterpret_cast<const float4*>(
                x + (size_t)grow * FIN + k0);
            float4 a0 = ap[0], a1 = ap[1], x0 = xp[0], x1 = xp[1];
            v[0] = fmaf(d2, x0.x, a0.x); v[1] = fmaf(d2, x0.y, a0.y);
            v[2] = fmaf(d2, x0.z, a0.z); v[3] = fmaf(d2, x0.w, a0.w);
            v[4] = fmaf(d2, x1.x, a1.x); v[5] = fmaf(d2, x1.y, a1.y);
            v[6] = fmaf(d2, x1.z, a1.z); v[7] = fmaf(d2, x1.w, a1.w);
        } else {
            #pragma unroll
            for (int j = 0; j < 8; ++j) v[j] = 0.0f;
        }
        #pragma unroll
        for (int j = 0; j < 8; ++j) xs[r][k0 + j] = v[j];
    }
    __syncthreads();

    // ---- stage A: hs = relu(xs @ W0 + b0) ----
    {
        int r0 = (t >> 5) * 4;          // 0..28
        int c0 = (t & 31) * 4;          // 0..124
        float4 bv = *reinterpret_cast<const float4*>(&b0[c0]);
        float acc[4][4];
        #pragma unroll
        for (int jr = 0; jr < 4; ++jr) {
            acc[jr][0] = bv.x; acc[jr][1] = bv.y;
            acc[jr][2] = bv.z; acc[jr][3] = bv.w;
        }
        #pragma unroll 4
        for (int k = 0; k < FIN; ++k) {
            float4 w = *reinterpret_cast<const float4*>(&wts[k * FHID + c0]);
            float x0 = xs[r0 + 0][k], x1 = xs[r0 + 1][k];
            float x2 = xs[r0 + 2][k], x3 = xs[r0 + 3][k];
            acc[0][0] = fmaf(x0, w.x, acc[0][0]);
            acc[0][1] = fmaf(x0, w.y, acc[0][1]);
            acc[0][2] = fmaf(x0, w.z, acc[0][2]);
            acc[0][3] = fmaf(x0, w.w, acc[0][3]);
            acc[1][0] = fmaf(x1, w.x, acc[1][0]);
            acc[1][1] = fmaf(x1, w.y, acc[1][1]);
            acc[1][2] = fmaf(x1, w.z, acc[1][2]);
            acc[1][3] = fmaf(x1, w.w, acc[1][3]);
            acc[2][0] = fmaf(x2, w.x, acc[2][0]);
            acc[2][1] = fmaf(x2, w.y, acc[2][1]);
            acc[2][2] = fmaf(x2, w.z, acc[2][2]);
            acc[2][3] = fmaf(x2, w.w, acc[2][3]);
            acc[3][0] = fmaf(x3, w.x, acc[3][0]);
            acc[3][1] = fmaf(x3, w.y, acc[3][1]);
            acc[3][2] = fmaf(x3, w.z, acc[3][2]);
            acc[3][3] = fmaf(x3, w.w, acc[3][3]);
        }
        #pragma unroll
        for (int jr = 0; jr < 4; ++jr)
            #pragma unroll
            for (int jc = 0; jc < 4; ++jc)
                hs[r0 + jr][c0 + jc] = fmaxf(acc[jr][jc], 0.0f);
    }
    __syncthreads();    // stage A done: wts reads + hs writes complete

    // overwrite W0 region with W1 from registers
    #pragma unroll
    for (int i = 0; i < 8; ++i)
        reinterpret_cast<float4*>(wts)[t + i * 256] = w1r[i];
    __syncthreads();

    // ---- stage B: agg_io = hs @ W1 (in place) ----
    {
        int r0 = (t >> 4) * 2;          // 0..30
        int c0 = (t & 15) * 4;          // 0..60
        float acc[2][4] = {{0.f, 0.f, 0.f, 0.f}, {0.f, 0.f, 0.f, 0.f}};
        #pragma unroll 4
        for (int k = 0; k < FHID; ++k) {
            float4 w = *reinterpret_cast<const float4*>(&wts[k * FOUT + c0]);
            float h0 = hs[r0 + 0][k], h1 = hs[r0 + 1][k];
            acc[0][0] = fmaf(h0, w.x, acc[0][0]);
            acc[0][1] = fmaf(h0, w.y, acc[0][1]);
            acc[0][2] = fmaf(h0, w.z, acc[0][2]);
            acc[0][3] = fmaf(h0, w.w, acc[0][3]);
            acc[1][0] = fmaf(h1, w.x, acc[1][0]);
            acc[1][1] = fmaf(h1, w.y, acc[1][1]);
            acc[1][2] = fmaf(h1, w.z, acc[1][2]);
            acc[1][3] = fmaf(h1, w.w, acc[1][3]);
        }
        #pragma unroll
        for (int jr = 0; jr < 2; ++jr) {
            int grow = row0 + r0 + jr;
            if (grow < n)
                *reinterpret_cast<float4*>(&agg_io[(size_t)grow * FOUT + c0]) =
                    make_float4(acc[jr][0], acc[jr][1], acc[jr][2], acc[jr][3]);
        }
    }
}

// out = sigmoid( out(=agg2) + dis^2 * hw1 + b1 )   in place
__global__ void k_final(float* __restrict__ out,
                        const float* __restrict__ hw1,
                        const float* __restrict__ dis,
                        const float* __restrict__ b1, int n) {
    int i = blockIdx.x * blockDim.x + threadIdx.x;
    if (i >= n * FOUT) return;
    int node = i >> 6, f = i & 63;
    float di = dis[node];
    float v = out[i] + di * di * hw1[i] + b1[f];
    out[i] = 1.0f / (1.0f + expf(-v));
}

extern "C" void kernel_launch(void* const* d_in, const int* in_sizes, int n_in,
                              void* d_out, int out_size, void* d_ws, size_t ws_size,
                              hipStream_t stream) {
    const float* x   = (const float*)d_in[0];
    const int*   ei  = (const int*)d_in[1];   // int32 [2, E]
    const float* W0  = (const float*)d_in[2];
    const float* b0  = (const float*)d_in[3];
    const float* W1  = (const float*)d_in[4];
    const float* b1  = (const float*)d_in[5];
    float*       out = (float*)d_out;

    const int n = in_sizes[0] / FIN;        // 100000
    const int e = in_sizes[1] / 2;          // 1600000
    const int* src = ei;
    const int* dst = ei + e;

    size_t need = ((size_t)n + (size_t)n * FIN) * sizeof(float);
    if (ws_size < need) return;
    float* dis = (float*)d_ws;
    float* buf = dis + n;                   // agg(x), then hw1 (in place)

    hipMemsetAsync(buf, 0, (size_t)n * FIN  * sizeof(float), stream);
    hipMemsetAsync(out, 0, (size_t)n * FOUT * sizeof(float), stream);

    k_deg_init<<<(n + 255) / 256, 256, 0, stream>>>(dis, n);
    k_deg_accum<<<(e + 255) / 256, 256, 0, stream>>>(dst, dis, e);
    k_rsqrt<<<(n + 255) / 256, 256, 0, stream>>>(dis, n);

    // layer 1 aggregation: buf = segment_sum(norm * x[src]) over dst
    {
        long long threads = (long long)e * 64;
        int blocks = (int)((threads + 255) / 256);
        k_edge_agg64<<<blocks, 256, 0, stream>>>(src, dst, dis, x, buf, e);
    }

    // fused MLP: buf = relu((buf + dis^2*x) @ W0 + b0) @ W1   (in place)
    k_mlp_v2<<<(n + PR - 1) / PR, 256, 0, stream>>>(x, buf, dis, W0, b0, W1, n);

    // layer 2 aggregation straight into d_out
    {
        long long threads = (long long)e * 64;
        int blocks = (int)((threads + 255) / 256);
        k_edge_agg64<<<blocks, 256, 0, stream>>>(src, dst, dis, buf, out, e);
    }

    k_final<<<(n * FOUT + 255) / 256, 256, 0, stream>>>(out, buf, dis, b1, n);
}

// Round 5
// 476.261 us; speedup vs baseline: 2.4921x; 1.8520x over previous
//
#include <hip/hip_runtime.h>
#include <math.h>

// 2-layer GCN, fp32: out = sigmoid(gcn(relu(gcn(x, W0, b0)), W1, b1))
// edge_index arrives int32. agg(x@W)==agg(x)@W -> aggregate raw x first.
// Round-5: atomic scatter (400MB HBM write-through per layer) replaced by
// pull-based CSR aggregation. CSR (row_ptr + dst-sorted src list) built once
// per call, used by BOTH layers. Pull kernel: one wave per dst node,
// lane=feature, register accumulate, single write; self-loop folded in;
// layer-2 instance also fuses +b1 and sigmoid.
// Workspace: dis[N] + buf[N*64] + counts[N] + row_ptr[N+1] + bsums[64]
//            + sorted_src[E] floats/ints = ~33.5 MB.

#define FIN 64
#define FHID 128
#define FOUT 64
#define PR 32          // rows per MLP panel
#define SCB 2048       // elements per scan block (256 thr x 8)

__global__ void k_count(const int* __restrict__ dst, int* __restrict__ cnt, int e) {
    int i = blockIdx.x * blockDim.x + threadIdx.x;
    if (i < e) atomicAdd(&cnt[dst[i]], 1);
}

// per-block exclusive scan of counts -> row_ptr (block-local), block totals
__global__ __launch_bounds__(256) void k_scan1(const int* __restrict__ cnt,
                                               int* __restrict__ rp,
                                               int* __restrict__ bsums, int n) {
    __shared__ int ssum[256];
    int t = threadIdx.x;
    int base = blockIdx.x * SCB + t * 8;
    int c[8], loc = 0;
    #pragma unroll
    for (int j = 0; j < 8; ++j) {
        c[j] = (base + j < n) ? cnt[base + j] : 0;
        loc += c[j];
    }
    ssum[t] = loc;
    __syncthreads();
    #pragma unroll
    for (int off = 1; off < 256; off <<= 1) {
        int v = (t >= off) ? ssum[t - off] : 0;
        __syncthreads();
        ssum[t] += v;
        __syncthreads();
    }
    int run = ssum[t] - loc;              // exclusive prefix of this thread
    #pragma unroll
    for (int j = 0; j < 8; ++j) {
        if (base + j < n) rp[base + j] = run;
        run += c[j];
    }
    if (t == 255) bsums[blockIdx.x] = ssum[255];
}

__global__ void k_scan2(int* __restrict__ bsums, int nb) {
    if (threadIdx.x == 0 && blockIdx.x == 0) {
        int run = 0;
        for (int i = 0; i < nb; ++i) { int v = bsums[i]; bsums[i] = run; run += v; }
    }
}

// fixup row_ptr with block offsets; dis = rsqrt(1+count); cursor = row_ptr.
// NOTE: cursor aliases counts (read counts first).
__global__ void k_scan3(int* __restrict__ rp, const int* __restrict__ bsums,
                        int* __restrict__ cursor /* == counts */,
                        float* __restrict__ dis, int n, int e) {
    int i = blockIdx.x * blockDim.x + threadIdx.x;
    if (i >= n) return;
    int c = cursor[i];                    // counts[i]
    dis[i] = rsqrtf(1.0f + (float)c);
    int r = rp[i] + bsums[i / SCB];
    rp[i] = r;
    cursor[i] = r;
    if (i == 0) rp[n] = e;
}

__global__ void k_fill(const int* __restrict__ src, const int* __restrict__ dst,
                       int* __restrict__ cursor, int* __restrict__ ssrc, int e) {
    int i = blockIdx.x * blockDim.x + threadIdx.x;
    if (i >= e) return;
    int pos = atomicAdd(&cursor[dst[i]], 1);
    ssrc[pos] = src[i];
}

// Pull aggregation: one 64-lane wave per dst node, lane = feature.
// outp[d][f] = dis[d] * ( dis[d]*feat[d][f] + sum_s dis[s]*feat[s][f] )
// sig=true: also += b1[f], apply sigmoid (layer-2 final output).
__global__ __launch_bounds__(256) void k_pull_agg(
        const int* __restrict__ rp, const int* __restrict__ ssrc,
        const float* __restrict__ dis, const float* __restrict__ feat,
        const float* __restrict__ b1, float* __restrict__ outp,
        int n, int sig) {
    int node = blockIdx.x * 4 + (threadIdx.x >> 6);
    if (node >= n) return;
    int f = threadIdx.x & 63;
    float dd = dis[node];
    float acc0 = dd * feat[(size_t)node * 64 + f];   // self-loop term
    float acc1 = 0.0f;
    int j = rp[node], end = rp[node + 1];
    for (; j + 1 < end; j += 2) {
        int s0 = ssrc[j], s1 = ssrc[j + 1];
        float w0 = dis[s0], w1 = dis[s1];
        acc0 = fmaf(w0, feat[(size_t)s0 * 64 + f], acc0);
        acc1 = fmaf(w1, feat[(size_t)s1 * 64 + f], acc1);
    }
    if (j < end) {
        int s = ssrc[j];
        acc0 = fmaf(dis[s], feat[(size_t)s * 64 + f], acc0);
    }
    float v = dd * (acc0 + acc1);
    if (sig) {
        v += b1[f];
        v = 1.0f / (1.0f + expf(-v));
    }
    outp[(size_t)node * 64 + f] = v;
}

// Register-tiled fused MLP, in place: buf = relu(buf@W0+b0)@W1.
// LDS: wts(32KB: W0 then W1) + xs[32][65] + hs[32][129] -> 2 blk/CU.
__global__ __launch_bounds__(256, 2) void k_mlp_v2(
        float* agg_io,
        const float* __restrict__ W0,       // [64][128]
        const float* __restrict__ b0,       // [128]
        const float* __restrict__ W1,       // [128][64]
        int n) {
    __shared__ float wts[FIN * FHID];
    __shared__ float xs[PR][FIN + 1];
    __shared__ float hs[PR][FHID + 1];
    int t = threadIdx.x;
    int row0 = blockIdx.x * PR;

    float4 w1r[8];
    #pragma unroll
    for (int i = 0; i < 8; ++i)
        w1r[i] = reinterpret_cast<const float4*>(W1)[t + i * 256];
    #pragma unroll
    for (int i = 0; i < 8; ++i)
        reinterpret_cast<float4*>(wts)[t + i * 256] =
            reinterpret_cast<const float4*>(W0)[t + i * 256];

    {   // xs = buf rows (already includes self-loop from pull)
        int r = t >> 3, k0 = (t & 7) * 8;
        int grow = row0 + r;
        float4 a0 = make_float4(0, 0, 0, 0), a1 = a0;
        if (grow < n) {
            const float4* ap = reinterpret_cast<const float4*>(
                agg_io + (size_t)grow * FIN + k0);
            a0 = ap[0]; a1 = ap[1];
        }
        xs[r][k0 + 0] = a0.x; xs[r][k0 + 1] = a0.y;
        xs[r][k0 + 2] = a0.z; xs[r][k0 + 3] = a0.w;
        xs[r][k0 + 4] = a1.x; xs[r][k0 + 5] = a1.y;
        xs[r][k0 + 6] = a1.z; xs[r][k0 + 7] = a1.w;
    }
    __syncthreads();

    {   // stage A: hs = relu(xs @ W0 + b0), 4x4 tile
        int r0 = (t >> 5) * 4;
        int c0 = (t & 31) * 4;
        float4 bv = *reinterpret_cast<const float4*>(&b0[c0]);
        float acc[4][4];
        #pragma unroll
        for (int jr = 0; jr < 4; ++jr) {
            acc[jr][0] = bv.x; acc[jr][1] = bv.y;
            acc[jr][2] = bv.z; acc[jr][3] = bv.w;
        }
        #pragma unroll 4
        for (int k = 0; k < FIN; ++k) {
            float4 w = *reinterpret_cast<const float4*>(&wts[k * FHID + c0]);
            float x0 = xs[r0 + 0][k], x1 = xs[r0 + 1][k];
            float x2 = xs[r0 + 2][k], x3 = xs[r0 + 3][k];
            acc[0][0] = fmaf(x0, w.x, acc[0][0]);
            acc[0][1] = fmaf(x0, w.y, acc[0][1]);
            acc[0][2] = fmaf(x0, w.z, acc[0][2]);
            acc[0][3] = fmaf(x0, w.w, acc[0][3]);
            acc[1][0] = fmaf(x1, w.x, acc[1][0]);
            acc[1][1] = fmaf(x1, w.y, acc[1][1]);
            acc[1][2] = fmaf(x1, w.z, acc[1][2]);
            acc[1][3] = fmaf(x1, w.w, acc[1][3]);
            acc[2][0] = fmaf(x2, w.x, acc[2][0]);
            acc[2][1] = fmaf(x2, w.y, acc[2][1]);
            acc[2][2] = fmaf(x2, w.z, acc[2][2]);
            acc[2][3] = fmaf(x2, w.w, acc[2][3]);
            acc[3][0] = fmaf(x3, w.x, acc[3][0]);
            acc[3][1] = fmaf(x3, w.y, acc[3][1]);
            acc[3][2] = fmaf(x3, w.z, acc[3][2]);
            acc[3][3] = fmaf(x3, w.w, acc[3][3]);
        }
        #pragma unroll
        for (int jr = 0; jr < 4; ++jr)
            #pragma unroll
            for (int jc = 0; jc < 4; ++jc)
                hs[r0 + jr][c0 + jc] = fmaxf(acc[jr][jc], 0.0f);
    }
    __syncthreads();

    #pragma unroll
    for (int i = 0; i < 8; ++i)
        reinterpret_cast<float4*>(wts)[t + i * 256] = w1r[i];
    __syncthreads();

    {   // stage B: agg_io = hs @ W1, 2x4 tile
        int r0 = (t >> 4) * 2;
        int c0 = (t & 15) * 4;
        float acc[2][4] = {{0.f, 0.f, 0.f, 0.f}, {0.f, 0.f, 0.f, 0.f}};
        #pragma unroll 4
        for (int k = 0; k < FHID; ++k) {
            float4 w = *reinterpret_cast<const float4*>(&wts[k * FOUT + c0]);
            float h0 = hs[r0 + 0][k], h1 = hs[r0 + 1][k];
            acc[0][0] = fmaf(h0, w.x, acc[0][0]);
            acc[0][1] = fmaf(h0, w.y, acc[0][1]);
            acc[0][2] = fmaf(h0, w.z, acc[0][2]);
            acc[0][3] = fmaf(h0, w.w, acc[0][3]);
            acc[1][0] = fmaf(h1, w.x, acc[1][0]);
            acc[1][1] = fmaf(h1, w.y, acc[1][1]);
            acc[1][2] = fmaf(h1, w.z, acc[1][2]);
            acc[1][3] = fmaf(h1, w.w, acc[1][3]);
        }
        #pragma unroll
        for (int jr = 0; jr < 2; ++jr) {
            int grow = row0 + r0 + jr;
            if (grow < n)
                *reinterpret_cast<float4*>(&agg_io[(size_t)grow * FOUT + c0]) =
                    make_float4(acc[jr][0], acc[jr][1], acc[jr][2], acc[jr][3]);
        }
    }
}

extern "C" void kernel_launch(void* const* d_in, const int* in_sizes, int n_in,
                              void* d_out, int out_size, void* d_ws, size_t ws_size,
                              hipStream_t stream) {
    const float* x   = (const float*)d_in[0];
    const int*   ei  = (const int*)d_in[1];   // int32 [2, E]
    const float* W0  = (const float*)d_in[2];
    const float* b0  = (const float*)d_in[3];
    const float* W1  = (const float*)d_in[4];
    const float* b1  = (const float*)d_in[5];
    float*       out = (float*)d_out;

    const int n = in_sizes[0] / FIN;        // 100000
    const int e = in_sizes[1] / 2;          // 1600000
    const int* src = ei;
    const int* dst = ei + e;
    const int nb = (n + SCB - 1) / SCB;     // scan blocks (49)

    // workspace layout
    float* dis    = (float*)d_ws;           // N
    float* buf    = dis + n;                // N*64 (16B-aligned: N*4 % 16 == 0)
    int*   counts = (int*)(buf + (size_t)n * FIN);   // N (becomes cursor)
    int*   rp     = counts + n;             // N+1
    int*   bsums  = rp + (n + 1);           // nb (<=64)
    int*   ssrc   = bsums + 64;             // E
    size_t need = (size_t)((char*)(ssrc + e) - (char*)d_ws);
    if (ws_size < need) return;

    // build CSR (once, reused by both layers) + dis
    hipMemsetAsync(counts, 0, (size_t)n * sizeof(int), stream);
    k_count<<<(e + 255) / 256, 256, 0, stream>>>(dst, counts, e);
    k_scan1<<<nb, 256, 0, stream>>>(counts, rp, bsums, n);
    k_scan2<<<1, 64, 0, stream>>>(bsums, nb);
    k_scan3<<<(n + 255) / 256, 256, 0, stream>>>(rp, bsums, counts, dis, n, e);
    k_fill<<<(e + 255) / 256, 256, 0, stream>>>(src, dst, counts, ssrc, e);

    // layer 1: buf = agg(x) incl self-loop
    k_pull_agg<<<(n + 3) / 4, 256, 0, stream>>>(rp, ssrc, dis, x, b1, buf, n, 0);
    // fused MLP in place: buf = relu(buf@W0+b0)@W1
    k_mlp_v2<<<(n + PR - 1) / PR, 256, 0, stream>>>(buf, W0, b0, W1, n);
    // layer 2: out = sigmoid(agg(buf) incl self-loop + b1)
    k_pull_agg<<<(n + 3) / 4, 256, 0, stream>>>(rp, ssrc, dis, buf, b1, out, n, 1);
}

// Round 6
// 392.084 us; speedup vs baseline: 3.0271x; 1.2147x over previous
//
#include <hip/hip_runtime.h>
#include <math.h>

// 2-layer GCN, fp32: out = sigmoid(gcn(relu(gcn(x, W0, b0)), W1, b1))
// edge_index arrives int32. agg(x@W)==agg(x)@W -> aggregate raw x first.
// CSR (row_ptr + dst-sorted src) built once, used by both pull layers.
// Round-6: (a) fused MLP re-tiled PR=16 -> 45.6KB LDS -> 3 blocks/CU, with
// XOR-swizzled W0 LDS layout (kills 4-way bank conflict); (b) k_fill made
// atomic-free via rank capture in k_count.
// Workspace: dis[N]+buf[N*64]+counts[N]+rp[N+1]+bsums[64]+ssrc[E]+rank[E]
//            = ~39.7 MB (guarded).

#define FIN 64
#define FHID 128
#define FOUT 64
#define PR 16          // rows per MLP panel
#define SCB 2048       // elements per scan block (256 thr x 8)

// W0 LDS column swizzle: flips bits 2-3 of the word-in-row index by bits 5-6.
// Lanes {m,m+8,m+16,m+24} (cols 0/32/64/96 + 4m) then land in disjoint banks.
__device__ __forceinline__ int sw128(int c) { return c ^ (((c >> 5) & 3) << 2); }

__global__ void k_count(const int* __restrict__ dst, int* __restrict__ cnt,
                        int* __restrict__ rank, int e) {
    int i = blockIdx.x * blockDim.x + threadIdx.x;
    if (i < e) rank[i] = atomicAdd(&cnt[dst[i]], 1);
}

// per-block exclusive scan of counts -> row_ptr (block-local), block totals
__global__ __launch_bounds__(256) void k_scan1(const int* __restrict__ cnt,
                                               int* __restrict__ rp,
                                               int* __restrict__ bsums, int n) {
    __shared__ int ssum[256];
    int t = threadIdx.x;
    int base = blockIdx.x * SCB + t * 8;
    int c[8], loc = 0;
    #pragma unroll
    for (int j = 0; j < 8; ++j) {
        c[j] = (base + j < n) ? cnt[base + j] : 0;
        loc += c[j];
    }
    ssum[t] = loc;
    __syncthreads();
    #pragma unroll
    for (int off = 1; off < 256; off <<= 1) {
        int v = (t >= off) ? ssum[t - off] : 0;
        __syncthreads();
        ssum[t] += v;
        __syncthreads();
    }
    int run = ssum[t] - loc;
    #pragma unroll
    for (int j = 0; j < 8; ++j) {
        if (base + j < n) rp[base + j] = run;
        run += c[j];
    }
    if (t == 255) bsums[blockIdx.x] = ssum[255];
}

__global__ void k_scan2(int* __restrict__ bsums, int nb) {
    if (threadIdx.x == 0 && blockIdx.x == 0) {
        int run = 0;
        for (int i = 0; i < nb; ++i) { int v = bsums[i]; bsums[i] = run; run += v; }
    }
}

__global__ void k_scan3(int* __restrict__ rp, const int* __restrict__ bsums,
                        const int* __restrict__ cnt, float* __restrict__ dis,
                        int n, int e) {
    int i = blockIdx.x * blockDim.x + threadIdx.x;
    if (i >= n) return;
    dis[i] = rsqrtf(1.0f + (float)cnt[i]);
    rp[i] = rp[i] + bsums[i / SCB];
    if (i == 0) rp[n] = e;
}

// atomic-free scatter: position = row start + captured rank
__global__ void k_fill(const int* __restrict__ src, const int* __restrict__ dst,
                       const int* __restrict__ rp, const int* __restrict__ rank,
                       int* __restrict__ ssrc, int e) {
    int i = blockIdx.x * blockDim.x + threadIdx.x;
    if (i >= e) return;
    ssrc[rp[dst[i]] + rank[i]] = src[i];
}

// Pull aggregation: one 64-lane wave per dst node, lane = feature.
// outp[d][f] = dis[d] * ( dis[d]*feat[d][f] + sum_s dis[s]*feat[s][f] )
// sig=true: += b1[f], sigmoid.
__global__ __launch_bounds__(256) void k_pull_agg(
        const int* __restrict__ rp, const int* __restrict__ ssrc,
        const float* __restrict__ dis, const float* __restrict__ feat,
        const float* __restrict__ b1, float* __restrict__ outp,
        int n, int sig) {
    int node = blockIdx.x * 4 + (threadIdx.x >> 6);
    if (node >= n) return;
    int f = threadIdx.x & 63;
    float dd = dis[node];
    float acc0 = dd * feat[(size_t)node * 64 + f];
    float acc1 = 0.0f;
    int j = rp[node], end = rp[node + 1];
    for (; j + 1 < end; j += 2) {
        int s0 = ssrc[j], s1 = ssrc[j + 1];
        float w0 = dis[s0], w1 = dis[s1];
        acc0 = fmaf(w0, feat[(size_t)s0 * 64 + f], acc0);
        acc1 = fmaf(w1, feat[(size_t)s1 * 64 + f], acc1);
    }
    if (j < end) {
        int s = ssrc[j];
        acc0 = fmaf(dis[s], feat[(size_t)s * 64 + f], acc0);
    }
    float v = dd * (acc0 + acc1);
    if (sig) {
        v += b1[f];
        v = 1.0f / (1.0f + expf(-v));
    }
    outp[(size_t)node * 64 + f] = v;
}

// Fused MLP, in place: buf = relu(buf@W0+b0)@W1.
// PR=16 panel, 256 threads. LDS: wts 32KB (W0 swizzled, then W1 linear)
// + xs[16][68] 4.25KB + hs[16][132] 8.25KB = 45.6KB -> 3 blocks/CU.
// Stage A: 2 rows x 4 cols/thread, swizzled conflict-free wts reads.
// Stage B: 1 row x 4 cols/thread, 2-way (free) wts reads.
__global__ __launch_bounds__(256, 3) void k_mlp_v3(
        float* agg_io,
        const float* __restrict__ W0,       // [64][128]
        const float* __restrict__ b0,       // [128]
        const float* __restrict__ W1,       // [128][64]
        int n) {
    __shared__ float wts[FIN * FHID];       // 8192 words
    __shared__ float xs[PR][FIN + 4];       // stride 68 words
    __shared__ float hs[PR][FHID + 4];      // stride 132 words
    int t = threadIdx.x;
    int row0 = blockIdx.x * PR;

    // preload W1 into regs (held through stage A; latency fully hidden)
    float4 w1r[8];
    #pragma unroll
    for (int i = 0; i < 8; ++i)
        w1r[i] = reinterpret_cast<const float4*>(W1)[t + i * 256];

    // stage W0 into LDS, swizzled
    #pragma unroll
    for (int i = 0; i < 8; ++i) {
        int w = (t + i * 256) * 4;          // linear word index
        int k = w >> 7, c = w & 127;
        *reinterpret_cast<float4*>(&wts[k * FHID + sw128(c)]) =
            reinterpret_cast<const float4*>(W0)[t + i * 256];
    }

    // xs fill: thread t -> row t>>4, word group (t&15)*4  (1 float4 each)
    {
        int r = t >> 4, k0 = (t & 15) * 4;
        int grow = row0 + r;
        float4 a = make_float4(0, 0, 0, 0);
        if (grow < n)
            a = *reinterpret_cast<const float4*>(agg_io + (size_t)grow * FIN + k0);
        *reinterpret_cast<float4*>(&xs[r][k0]) = a;
    }
    __syncthreads();

    // ---- stage A: hs = relu(xs @ W0 + b0), 2x4 tile ----
    {
        int r0 = (t >> 5) * 2;              // 0..14
        int c0 = (t & 31) * 4;              // 0..124 (true column)
        int c0s = sw128(c0);                // swizzled LDS offset
        float4 bv = *reinterpret_cast<const float4*>(&b0[c0]);
        float acc[2][4];
        acc[0][0] = bv.x; acc[0][1] = bv.y; acc[0][2] = bv.z; acc[0][3] = bv.w;
        acc[1][0] = bv.x; acc[1][1] = bv.y; acc[1][2] = bv.z; acc[1][3] = bv.w;
        #pragma unroll 8
        for (int k = 0; k < FIN; ++k) {
            float4 w = *reinterpret_cast<const float4*>(&wts[k * FHID + c0s]);
            float x0 = xs[r0 + 0][k], x1 = xs[r0 + 1][k];
            acc[0][0] = fmaf(x0, w.x, acc[0][0]);
            acc[0][1] = fmaf(x0, w.y, acc[0][1]);
            acc[0][2] = fmaf(x0, w.z, acc[0][2]);
            acc[0][3] = fmaf(x0, w.w, acc[0][3]);
            acc[1][0] = fmaf(x1, w.x, acc[1][0]);
            acc[1][1] = fmaf(x1, w.y, acc[1][1]);
            acc[1][2] = fmaf(x1, w.z, acc[1][2]);
            acc[1][3] = fmaf(x1, w.w, acc[1][3]);
        }
        *reinterpret_cast<float4*>(&hs[r0 + 0][c0]) =
            make_float4(fmaxf(acc[0][0], 0.f), fmaxf(acc[0][1], 0.f),
                        fmaxf(acc[0][2], 0.f), fmaxf(acc[0][3], 0.f));
        *reinterpret_cast<float4*>(&hs[r0 + 1][c0]) =
            make_float4(fmaxf(acc[1][0], 0.f), fmaxf(acc[1][1], 0.f),
                        fmaxf(acc[1][2], 0.f), fmaxf(acc[1][3], 0.f));
    }
    __syncthreads();

    // overwrite wts with W1 (linear layout) from registers
    #pragma unroll
    for (int i = 0; i < 8; ++i)
        reinterpret_cast<float4*>(wts)[t + i * 256] = w1r[i];
    __syncthreads();

    // ---- stage B: agg_io = hs @ W1, 1x4 tile ----
    {
        int r  = t >> 4;                    // 0..15
        int c0 = (t & 15) * 4;              // 0..60
        float acc[4] = {0.f, 0.f, 0.f, 0.f};
        #pragma unroll 8
        for (int k = 0; k < FHID; ++k) {
            float4 w = *reinterpret_cast<const float4*>(&wts[k * FOUT + c0]);
            float h = hs[r][k];
            acc[0] = fmaf(h, w.x, acc[0]);
            acc[1] = fmaf(h, w.y, acc[1]);
            acc[2] = fmaf(h, w.z, acc[2]);
            acc[3] = fmaf(h, w.w, acc[3]);
        }
        int grow = row0 + r;
        if (grow < n)
            *reinterpret_cast<float4*>(&agg_io[(size_t)grow * FOUT + c0]) =
                make_float4(acc[0], acc[1], acc[2], acc[3]);
    }
}

extern "C" void kernel_launch(void* const* d_in, const int* in_sizes, int n_in,
                              void* d_out, int out_size, void* d_ws, size_t ws_size,
                              hipStream_t stream) {
    const float* x   = (const float*)d_in[0];
    const int*   ei  = (const int*)d_in[1];   // int32 [2, E]
    const float* W0  = (const float*)d_in[2];
    const float* b0  = (const float*)d_in[3];
    const float* W1  = (const float*)d_in[4];
    const float* b1  = (const float*)d_in[5];
    float*       out = (float*)d_out;

    const int n = in_sizes[0] / FIN;        // 100000
    const int e = in_sizes[1] / 2;          // 1600000
    const int* src = ei;
    const int* dst = ei + e;
    const int nb = (n + SCB - 1) / SCB;     // 49 scan blocks

    // workspace layout
    float* dis    = (float*)d_ws;           // N
    float* buf    = dis + n;                // N*64
    int*   counts = (int*)(buf + (size_t)n * FIN);   // N
    int*   rp     = counts + n;             // N+1
    int*   bsums  = rp + (n + 1);           // <=64
    int*   ssrc   = bsums + 64;             // E
    int*   rank   = ssrc + e;               // E
    size_t need = (size_t)((char*)(rank + e) - (char*)d_ws);
    if (ws_size < need) return;

    // build CSR + dis
    hipMemsetAsync(counts, 0, (size_t)n * sizeof(int), stream);
    k_count<<<(e + 255) / 256, 256, 0, stream>>>(dst, counts, rank, e);
    k_scan1<<<nb, 256, 0, stream>>>(counts, rp, bsums, n);
    k_scan2<<<1, 64, 0, stream>>>(bsums, nb);
    k_scan3<<<(n + 255) / 256, 256, 0, stream>>>(rp, bsums, counts, dis, n, e);
    k_fill<<<(e + 255) / 256, 256, 0, stream>>>(src, dst, rp, rank, ssrc, e);

    // layer 1: buf = agg(x) incl self-loop
    k_pull_agg<<<(n + 3) / 4, 256, 0, stream>>>(rp, ssrc, dis, x, b1, buf, n, 0);
    // fused MLP in place: buf = relu(buf@W0+b0)@W1
    k_mlp_v3<<<(n + PR - 1) / PR, 256, 0, stream>>>(buf, W0, b0, W1, n);
    // layer 2: out = sigmoid(agg(buf) incl self-loop + b1)
    k_pull_agg<<<(n + 3) / 4, 256, 0, stream>>>(rp, ssrc, dis, buf, b1, out, n, 1);
}

// Round 7
// 347.714 us; speedup vs baseline: 3.4134x; 1.1276x over previous
//
#include <hip/hip_runtime.h>
#include <math.h>

// 2-layer GCN, fp32: out = sigmoid(gcn(relu(gcn(x, W0, b0)), W1, b1))
// edge_index arrives int32. agg(x@W)==agg(x)@W -> aggregate raw x first.
// CSR (row_ptr + dst-sorted src) built once per call, used by both pull layers.
// Round-7: fused MLP (pathological: VALUBusy 1.2%, 9x write amplification)
// replaced by two barrier-free register-weight GEMM kernels, one row per
// wave, scalar (readfirstlane) row loads. pull_agg: scalarized index loads
// + 4-way unrolled accumulator chains.
// Split path needs ~84.4MB ws (h[N*128] overlays dead rank[E]); falls back
// to fused MLP if ws_size too small.

#define FIN 64
#define FHID 128
#define FOUT 64
#define SCB 2048       // elements per scan block (256 thr x 8)
#define PR 16          // rows per fused-MLP panel (fallback path)

__device__ __forceinline__ int sw128(int c) { return c ^ (((c >> 5) & 3) << 2); }

// ---------------- CSR build ----------------

__global__ void k_count(const int* __restrict__ dst, int* __restrict__ cnt,
                        int* __restrict__ rank, int e) {
    int i = blockIdx.x * blockDim.x + threadIdx.x;
    if (i < e) rank[i] = atomicAdd(&cnt[dst[i]], 1);
}

__global__ __launch_bounds__(256) void k_scan1(const int* __restrict__ cnt,
                                               int* __restrict__ rp,
                                               int* __restrict__ bsums, int n) {
    __shared__ int ssum[256];
    int t = threadIdx.x;
    int base = blockIdx.x * SCB + t * 8;
    int c[8], loc = 0;
    #pragma unroll
    for (int j = 0; j < 8; ++j) {
        c[j] = (base + j < n) ? cnt[base + j] : 0;
        loc += c[j];
    }
    ssum[t] = loc;
    __syncthreads();
    #pragma unroll
    for (int off = 1; off < 256; off <<= 1) {
        int v = (t >= off) ? ssum[t - off] : 0;
        __syncthreads();
        ssum[t] += v;
        __syncthreads();
    }
    int run = ssum[t] - loc;
    #pragma unroll
    for (int j = 0; j < 8; ++j) {
        if (base + j < n) rp[base + j] = run;
        run += c[j];
    }
    if (t == 255) bsums[blockIdx.x] = ssum[255];
}

__global__ void k_scan2(int* __restrict__ bsums, int nb) {
    if (threadIdx.x == 0 && blockIdx.x == 0) {
        int run = 0;
        for (int i = 0; i < nb; ++i) { int v = bsums[i]; bsums[i] = run; run += v; }
    }
}

__global__ void k_scan3(int* __restrict__ rp, const int* __restrict__ bsums,
                        const int* __restrict__ cnt, float* __restrict__ dis,
                        int n, int e) {
    int i = blockIdx.x * blockDim.x + threadIdx.x;
    if (i >= n) return;
    dis[i] = rsqrtf(1.0f + (float)cnt[i]);
    rp[i] = rp[i] + bsums[i / SCB];
    if (i == 0) rp[n] = e;
}

__global__ void k_fill(const int* __restrict__ src, const int* __restrict__ dst,
                       const int* __restrict__ rp, const int* __restrict__ rank,
                       int* __restrict__ ssrc, int e) {
    int i = blockIdx.x * blockDim.x + threadIdx.x;
    if (i >= e) return;
    ssrc[rp[dst[i]] + rank[i]] = src[i];
}

// ---------------- pull aggregation ----------------
// One 64-lane wave per dst node, lane = feature. Index/weight loads are
// wave-uniform (readfirstlane'd node) -> scalar s_loads; 4 independent
// accumulator chains for memory-level parallelism on the 256B row gathers.
__global__ __launch_bounds__(256) void k_pull_agg(
        const int* __restrict__ rp, const int* __restrict__ ssrc,
        const float* __restrict__ dis, const float* __restrict__ feat,
        const float* __restrict__ b1, float* __restrict__ outp,
        int n, int sig) {
    int node4 = blockIdx.x * 4 + (threadIdx.x >> 6);
    if (node4 >= n) return;
    int node = __builtin_amdgcn_readfirstlane(node4);
    int f = threadIdx.x & 63;
    float dd = dis[node];
    float acc0 = dd * feat[(size_t)node * 64 + f];   // self-loop
    float acc1 = 0.0f, acc2 = 0.0f, acc3 = 0.0f;
    int j = rp[node], end = rp[node + 1];
    for (; j + 3 < end; j += 4) {
        int s0 = ssrc[j], s1 = ssrc[j + 1], s2 = ssrc[j + 2], s3 = ssrc[j + 3];
        float w0 = dis[s0], w1 = dis[s1], w2 = dis[s2], w3 = dis[s3];
        acc0 = fmaf(w0, feat[(size_t)s0 * 64 + f], acc0);
        acc1 = fmaf(w1, feat[(size_t)s1 * 64 + f], acc1);
        acc2 = fmaf(w2, feat[(size_t)s2 * 64 + f], acc2);
        acc3 = fmaf(w3, feat[(size_t)s3 * 64 + f], acc3);
    }
    for (; j < end; ++j) {
        int s = ssrc[j];
        acc0 = fmaf(dis[s], feat[(size_t)s * 64 + f], acc0);
    }
    float v = dd * ((acc0 + acc1) + (acc2 + acc3));
    if (sig) {
        v += b1[f];
        v = 1.0f / (1.0f + expf(-v));
    }
    outp[(size_t)node * 64 + f] = v;
}

// ---------------- split MLP (register-weight GEMMs) ----------------
// G1: h[N][128] = relu(buf[N][64] @ W0 + b0).
// One wave per (row, col-half). Lane owns output col = half*64 + lane; its
// weight column W0[:,col] (64 floats) lives in VGPRs, loaded once per wave
// (half is fixed per wave across the grid-stride loop). Row inputs are
// wave-uniform scalar loads overlapping the FMA chain. No LDS, no barriers.
__global__ __launch_bounds__(256) void k_gemm1(
        const float* __restrict__ in,      // [n][64]
        const float* __restrict__ W0,      // [64][128]
        const float* __restrict__ b0,      // [128]
        float* __restrict__ h,             // [n][128]
        int n, int nwaves) {
    int gw = blockIdx.x * 4 + (threadIdx.x >> 6);   // global wave id
    int lane = threadIdx.x & 63;
    int half = gw & 1;
    int col = half * 64 + lane;

    float w0r[64];
    #pragma unroll
    for (int k = 0; k < 64; ++k) w0r[k] = W0[k * FHID + col];
    float bias = b0[col];

    for (int task = gw; task < 2 * n; task += nwaves) {
        int row = __builtin_amdgcn_readfirstlane(task >> 1);
        const float* srow = in + (size_t)row * FIN;
        float acc = bias;
        #pragma unroll
        for (int k = 0; k < 64; ++k) acc = fmaf(srow[k], w0r[k], acc);
        h[(size_t)row * FHID + col] = fmaxf(acc, 0.0f);
    }
}

// G2: outb[N][64] = h[N][128] @ W1. One wave per row; lane owns col = lane;
// W1[:,col] (128 floats) in VGPRs.
__global__ __launch_bounds__(256) void k_gemm2(
        const float* __restrict__ h,       // [n][128]
        const float* __restrict__ W1,      // [128][64]
        float* __restrict__ outb,          // [n][64]
        int n, int nwaves) {
    int gw = blockIdx.x * 4 + (threadIdx.x >> 6);
    int lane = threadIdx.x & 63;

    float w1r[128];
    #pragma unroll
    for (int k = 0; k < 128; ++k) w1r[k] = W1[k * FOUT + lane];

    for (int task = gw; task < n; task += nwaves) {
        int row = __builtin_amdgcn_readfirstlane(task);
        const float* hrow = h + (size_t)row * FHID;
        float acc = 0.0f;
        #pragma unroll
        for (int k = 0; k < 128; ++k) acc = fmaf(hrow[k], w1r[k], acc);
        outb[(size_t)row * FOUT + lane] = acc;
    }
}

// ---------------- fallback fused MLP (ws too small) ----------------
__global__ __launch_bounds__(256, 3) void k_mlp_v3(
        float* agg_io,
        const float* __restrict__ W0, const float* __restrict__ b0,
        const float* __restrict__ W1, int n) {
    __shared__ float wts[FIN * FHID];
    __shared__ float xs[PR][FIN + 4];
    __shared__ float hs[PR][FHID + 4];
    int t = threadIdx.x;
    int row0 = blockIdx.x * PR;
    float4 w1r[8];
    #pragma unroll
    for (int i = 0; i < 8; ++i)
        w1r[i] = reinterpret_cast<const float4*>(W1)[t + i * 256];
    #pragma unroll
    for (int i = 0; i < 8; ++i) {
        int w = (t + i * 256) * 4;
        int k = w >> 7, c = w & 127;
        *reinterpret_cast<float4*>(&wts[k * FHID + sw128(c)]) =
            reinterpret_cast<const float4*>(W0)[t + i * 256];
    }
    {
        int r = t >> 4, k0 = (t & 15) * 4;
        int grow = row0 + r;
        float4 a = make_float4(0, 0, 0, 0);
        if (grow < n)
            a = *reinterpret_cast<const float4*>(agg_io + (size_t)grow * FIN + k0);
        *reinterpret_cast<float4*>(&xs[r][k0]) = a;
    }
    __syncthreads();
    {
        int r0 = (t >> 5) * 2;
        int c0 = (t & 31) * 4;
        int c0s = sw128(c0);
        float4 bv = *reinterpret_cast<const float4*>(&b0[c0]);
        float acc[2][4];
        acc[0][0] = bv.x; acc[0][1] = bv.y; acc[0][2] = bv.z; acc[0][3] = bv.w;
        acc[1][0] = bv.x; acc[1][1] = bv.y; acc[1][2] = bv.z; acc[1][3] = bv.w;
        #pragma unroll 8
        for (int k = 0; k < FIN; ++k) {
            float4 w = *reinterpret_cast<const float4*>(&wts[k * FHID + c0s]);
            float x0 = xs[r0 + 0][k], x1 = xs[r0 + 1][k];
            acc[0][0] = fmaf(x0, w.x, acc[0][0]);
            acc[0][1] = fmaf(x0, w.y, acc[0][1]);
            acc[0][2] = fmaf(x0, w.z, acc[0][2]);
            acc[0][3] = fmaf(x0, w.w, acc[0][3]);
            acc[1][0] = fmaf(x1, w.x, acc[1][0]);
            acc[1][1] = fmaf(x1, w.y, acc[1][1]);
            acc[1][2] = fmaf(x1, w.z, acc[1][2]);
            acc[1][3] = fmaf(x1, w.w, acc[1][3]);
        }
        *reinterpret_cast<float4*>(&hs[r0 + 0][c0]) =
            make_float4(fmaxf(acc[0][0], 0.f), fmaxf(acc[0][1], 0.f),
                        fmaxf(acc[0][2], 0.f), fmaxf(acc[0][3], 0.f));
        *reinterpret_cast<float4*>(&hs[r0 + 1][c0]) =
            make_float4(fmaxf(acc[1][0], 0.f), fmaxf(acc[1][1], 0.f),
                        fmaxf(acc[1][2], 0.f), fmaxf(acc[1][3], 0.f));
    }
    __syncthreads();
    #pragma unroll
    for (int i = 0; i < 8; ++i)
        reinterpret_cast<float4*>(wts)[t + i * 256] = w1r[i];
    __syncthreads();
    {
        int r  = t >> 4;
        int c0 = (t & 15) * 4;
        float acc[4] = {0.f, 0.f, 0.f, 0.f};
        #pragma unroll 8
        for (int k = 0; k < FHID; ++k) {
            float4 w = *reinterpret_cast<const float4*>(&wts[k * FOUT + c0]);
            float h = hs[r][k];
            acc[0] = fmaf(h, w.x, acc[0]);
            acc[1] = fmaf(h, w.y, acc[1]);
            acc[2] = fmaf(h, w.z, acc[2]);
            acc[3] = fmaf(h, w.w, acc[3]);
        }
        int grow = row0 + r;
        if (grow < n)
            *reinterpret_cast<float4*>(&agg_io[(size_t)grow * FOUT + c0]) =
                make_float4(acc[0], acc[1], acc[2], acc[3]);
    }
}

extern "C" void kernel_launch(void* const* d_in, const int* in_sizes, int n_in,
                              void* d_out, int out_size, void* d_ws, size_t ws_size,
                              hipStream_t stream) {
    const float* x   = (const float*)d_in[0];
    const int*   ei  = (const int*)d_in[1];   // int32 [2, E]
    const float* W0  = (const float*)d_in[2];
    const float* b0  = (const float*)d_in[3];
    const float* W1  = (const float*)d_in[4];
    const float* b1  = (const float*)d_in[5];
    float*       out = (float*)d_out;

    const int n = in_sizes[0] / FIN;        // 100000
    const int e = in_sizes[1] / 2;          // 1600000
    const int* src = ei;
    const int* dst = ei + e;
    const int nb = (n + SCB - 1) / SCB;

    // workspace layout
    float* dis    = (float*)d_ws;                    // N
    float* buf    = dis + n;                         // N*64
    int*   counts = (int*)(buf + (size_t)n * FIN);   // N
    int*   rp     = counts + n;                      // N+1
    int*   bsums  = rp + (n + 1);                    // <=64
    int*   ssrc   = bsums + 64;                      // E
    int*   rank   = ssrc + e;                        // E (dead after k_fill)
    float* h      = (float*)rank;                    // N*128 overlays rank+
    size_t base_need  = (size_t)((char*)rank - (char*)d_ws);
    size_t need_split = base_need +
        ((size_t)e * sizeof(int) > (size_t)n * FHID * sizeof(float)
             ? (size_t)e * sizeof(int) : (size_t)n * FHID * sizeof(float));
    size_t need_fused = base_need + (size_t)e * sizeof(int);
    if (ws_size < need_fused) return;
    const bool use_split = (ws_size >= need_split);

    // build CSR + dis
    hipMemsetAsync(counts, 0, (size_t)n * sizeof(int), stream);
    k_count<<<(e + 255) / 256, 256, 0, stream>>>(dst, counts, rank, e);
    k_scan1<<<nb, 256, 0, stream>>>(counts, rp, bsums, n);
    k_scan2<<<1, 64, 0, stream>>>(bsums, nb);
    k_scan3<<<(n + 255) / 256, 256, 0, stream>>>(rp, bsums, counts, dis, n, e);
    k_fill<<<(e + 255) / 256, 256, 0, stream>>>(src, dst, rp, rank, ssrc, e);

    // layer 1: buf = agg(x) incl self-loop
    k_pull_agg<<<(n + 3) / 4, 256, 0, stream>>>(rp, ssrc, dis, x, b1, buf, n, 0);

    if (use_split) {
        const int blocks = 2048, nwaves = blocks * 4;
        k_gemm1<<<blocks, 256, 0, stream>>>(buf, W0, b0, h, n, nwaves);
        k_gemm2<<<blocks, 256, 0, stream>>>(h, W1, buf, n, nwaves);
    } else {
        k_mlp_v3<<<(n + PR - 1) / PR, 256, 0, stream>>>(buf, W0, b0, W1, n);
    }

    // layer 2: out = sigmoid(agg(buf) incl self-loop + b1)
    k_pull_agg<<<(n + 3) / 4, 256, 0, stream>>>(rp, ssrc, dis, buf, b1, out, n, 1);
}

// Round 8
// 317.018 us; speedup vs baseline: 3.7439x; 1.0968x over previous
//
#include <hip/hip_runtime.h>
#include <hip/hip_fp16.h>
#include <math.h>

// 2-layer GCN, fp32: out = sigmoid(gcn(relu(gcn(x, W0, b0)), W1, b1))
// edge_index arrives int32. agg(x@W)==agg(x)@W -> aggregate raw x first.
// CSR (row_ptr + dst-sorted src) built once per call, reused by both layers.
// Round-8: pulls are gather-byte-bound (FETCH 194MB @ ~2.2TB/s). Gather
// fp16 scaled tables instead: y1 = fp16(dis*x), y2 = fp16(dis*(h@W1));
// agg[d] = dis[d]*(y[d] + sum y[s]) -> 128B/edge, no per-edge dis load.
// Hidden h stored fp16 too. Split path ws ~72MB; fp32 fused fallback kept.

#define FIN 64
#define FHID 128
#define FOUT 64
#define SCB 2048       // elements per scan block (256 thr x 8)
#define PR 16          // rows per fused-MLP panel (fallback path)

__device__ __forceinline__ int sw128(int c) { return c ^ (((c >> 5) & 3) << 2); }

// ---------------- CSR build ----------------

__global__ void k_count(const int* __restrict__ dst, int* __restrict__ cnt,
                        int* __restrict__ rank, int e) {
    int i = blockIdx.x * blockDim.x + threadIdx.x;
    if (i < e) rank[i] = atomicAdd(&cnt[dst[i]], 1);
}

__global__ __launch_bounds__(256) void k_scan1(const int* __restrict__ cnt,
                                               int* __restrict__ rp,
                                               int* __restrict__ bsums, int n) {
    __shared__ int ssum[256];
    int t = threadIdx.x;
    int base = blockIdx.x * SCB + t * 8;
    int c[8], loc = 0;
    #pragma unroll
    for (int j = 0; j < 8; ++j) {
        c[j] = (base + j < n) ? cnt[base + j] : 0;
        loc += c[j];
    }
    ssum[t] = loc;
    __syncthreads();
    #pragma unroll
    for (int off = 1; off < 256; off <<= 1) {
        int v = (t >= off) ? ssum[t - off] : 0;
        __syncthreads();
        ssum[t] += v;
        __syncthreads();
    }
    int run = ssum[t] - loc;
    #pragma unroll
    for (int j = 0; j < 8; ++j) {
        if (base + j < n) rp[base + j] = run;
        run += c[j];
    }
    if (t == 255) bsums[blockIdx.x] = ssum[255];
}

__global__ void k_scan2(int* __restrict__ bsums, int nb) {
    if (threadIdx.x == 0 && blockIdx.x == 0) {
        int run = 0;
        for (int i = 0; i < nb; ++i) { int v = bsums[i]; bsums[i] = run; run += v; }
    }
}

__global__ void k_scan3(int* __restrict__ rp, const int* __restrict__ bsums,
                        const int* __restrict__ cnt, float* __restrict__ dis,
                        int n, int e) {
    int i = blockIdx.x * blockDim.x + threadIdx.x;
    if (i >= n) return;
    dis[i] = rsqrtf(1.0f + (float)cnt[i]);
    rp[i] = rp[i] + bsums[i / SCB];
    if (i == 0) rp[n] = e;
}

__global__ void k_fill(const int* __restrict__ src, const int* __restrict__ dst,
                       const int* __restrict__ rp, const int* __restrict__ rank,
                       int* __restrict__ ssrc, int e) {
    int i = blockIdx.x * blockDim.x + threadIdx.x;
    if (i >= e) return;
    ssrc[rp[dst[i]] + rank[i]] = src[i];
}

// ---------------- fp16 scaled-feature table ----------------
// yh[node][f] = fp16( dis[node] * x[node][f] );  4 elems/thread
__global__ void k_toy(const float* __restrict__ x, const float* __restrict__ dis,
                      __half* __restrict__ yh, int n) {
    int gid = blockIdx.x * blockDim.x + threadIdx.x;
    if (gid >= n * 16) return;             // n*64/4
    int node = gid >> 4;
    float d = dis[node];
    float4 v = reinterpret_cast<const float4*>(x)[gid];
    __half2 h0, h1;
    h0.x = __float2half(d * v.x); h0.y = __float2half(d * v.y);
    h1.x = __float2half(d * v.z); h1.y = __float2half(d * v.w);
    reinterpret_cast<__half2*>(yh)[gid * 2 + 0] = h0;
    reinterpret_cast<__half2*>(yh)[gid * 2 + 1] = h1;
}

// ---------------- fp16 pull aggregation ----------------
// One wave per dst node, lane = feature. outp[d][f] =
//   dis[d] * ( yh[d][f] + sum_s yh[s][f] )   (+b1, sigmoid if sig)
__global__ __launch_bounds__(256) void k_pull16(
        const int* __restrict__ rp, const int* __restrict__ ssrc,
        const float* __restrict__ dis, const __half* __restrict__ yh,
        const float* __restrict__ b1, float* __restrict__ outp,
        int n, int sig) {
    int node4 = blockIdx.x * 4 + (threadIdx.x >> 6);
    if (node4 >= n) return;
    int node = __builtin_amdgcn_readfirstlane(node4);
    int f = threadIdx.x & 63;
    float acc0 = __half2float(yh[(size_t)node * 64 + f]);   // self-loop term
    float acc1 = 0.0f, acc2 = 0.0f, acc3 = 0.0f;
    int j = rp[node], end = rp[node + 1];
    for (; j + 3 < end; j += 4) {
        int s0 = ssrc[j], s1 = ssrc[j + 1], s2 = ssrc[j + 2], s3 = ssrc[j + 3];
        acc0 += __half2float(yh[(size_t)s0 * 64 + f]);
        acc1 += __half2float(yh[(size_t)s1 * 64 + f]);
        acc2 += __half2float(yh[(size_t)s2 * 64 + f]);
        acc3 += __half2float(yh[(size_t)s3 * 64 + f]);
    }
    for (; j < end; ++j)
        acc0 += __half2float(yh[(size_t)ssrc[j] * 64 + f]);
    float v = dis[node] * ((acc0 + acc1) + (acc2 + acc3));
    if (sig) {
        v += b1[f];
        v = 1.0f / (1.0f + expf(-v));
    }
    outp[(size_t)node * 64 + f] = v;
}

// ---------------- split MLP (register-weight GEMMs) ----------------
// G1: hh[N][128] = fp16( relu(buf[N][64] @ W0 + b0) ). One wave per
// (row, col-half); weight column in VGPRs; row inputs wave-uniform.
__global__ __launch_bounds__(256) void k_gemm1(
        const float* __restrict__ in,      // [n][64] fp32
        const float* __restrict__ W0,      // [64][128]
        const float* __restrict__ b0,      // [128]
        __half* __restrict__ h,            // [n][128] fp16
        int n, int nwaves) {
    int gw = blockIdx.x * 4 + (threadIdx.x >> 6);
    int lane = threadIdx.x & 63;
    int half_ = gw & 1;
    int col = half_ * 64 + lane;

    float w0r[64];
    #pragma unroll
    for (int k = 0; k < 64; ++k) w0r[k] = W0[k * FHID + col];
    float bias = b0[col];

    for (int task = gw; task < 2 * n; task += nwaves) {
        int row = __builtin_amdgcn_readfirstlane(task >> 1);
        const float* srow = in + (size_t)row * FIN;
        float acc = bias;
        #pragma unroll
        for (int k = 0; k < 64; ++k) acc = fmaf(srow[k], w0r[k], acc);
        h[(size_t)row * FHID + col] = __float2half(fmaxf(acc, 0.0f));
    }
}

// G2: yh[N][64] = fp16( dis[row] * (hh[row] @ W1) ). One wave per row.
__global__ __launch_bounds__(256) void k_gemm2(
        const __half* __restrict__ h,      // [n][128] fp16
        const float* __restrict__ W1,      // [128][64]
        const float* __restrict__ dis,
        __half* __restrict__ yh,           // [n][64] fp16
        int n, int nwaves) {
    int gw = blockIdx.x * 4 + (threadIdx.x >> 6);
    int lane = threadIdx.x & 63;

    float w1r[128];
    #pragma unroll
    for (int k = 0; k < 128; ++k) w1r[k] = W1[k * FOUT + lane];

    for (int task = gw; task < n; task += nwaves) {
        int row = __builtin_amdgcn_readfirstlane(task);
        const __half2* hrow = reinterpret_cast<const __half2*>(
            h + (size_t)row * FHID);
        float acc = 0.0f;
        #pragma unroll
        for (int k = 0; k < 64; ++k) {
            __half2 hv = hrow[k];
            acc = fmaf(__half2float(hv.x), w1r[2 * k + 0], acc);
            acc = fmaf(__half2float(hv.y), w1r[2 * k + 1], acc);
        }
        yh[(size_t)row * FOUT + lane] = __float2half(dis[row] * acc);
    }
}

// ---------------- fp32 fallback (ws too small) ----------------
__global__ __launch_bounds__(256) void k_pull_agg(
        const int* __restrict__ rp, const int* __restrict__ ssrc,
        const float* __restrict__ dis, const float* __restrict__ feat,
        const float* __restrict__ b1, float* __restrict__ outp,
        int n, int sig) {
    int node4 = blockIdx.x * 4 + (threadIdx.x >> 6);
    if (node4 >= n) return;
    int node = __builtin_amdgcn_readfirstlane(node4);
    int f = threadIdx.x & 63;
    float dd = dis[node];
    float acc0 = dd * feat[(size_t)node * 64 + f];
    float acc1 = 0.0f, acc2 = 0.0f, acc3 = 0.0f;
    int j = rp[node], end = rp[node + 1];
    for (; j + 3 < end; j += 4) {
        int s0 = ssrc[j], s1 = ssrc[j + 1], s2 = ssrc[j + 2], s3 = ssrc[j + 3];
        float w0 = dis[s0], w1 = dis[s1], w2 = dis[s2], w3 = dis[s3];
        acc0 = fmaf(w0, feat[(size_t)s0 * 64 + f], acc0);
        acc1 = fmaf(w1, feat[(size_t)s1 * 64 + f], acc1);
        acc2 = fmaf(w2, feat[(size_t)s2 * 64 + f], acc2);
        acc3 = fmaf(w3, feat[(size_t)s3 * 64 + f], acc3);
    }
    for (; j < end; ++j) {
        int s = ssrc[j];
        acc0 = fmaf(dis[s], feat[(size_t)s * 64 + f], acc0);
    }
    float v = dd * ((acc0 + acc1) + (acc2 + acc3));
    if (sig) {
        v += b1[f];
        v = 1.0f / (1.0f + expf(-v));
    }
    outp[(size_t)node * 64 + f] = v;
}

__global__ __launch_bounds__(256, 3) void k_mlp_v3(
        float* agg_io,
        const float* __restrict__ W0, const float* __restrict__ b0,
        const float* __restrict__ W1, int n) {
    __shared__ float wts[FIN * FHID];
    __shared__ float xs[PR][FIN + 4];
    __shared__ float hs[PR][FHID + 4];
    int t = threadIdx.x;
    int row0 = blockIdx.x * PR;
    float4 w1r[8];
    #pragma unroll
    for (int i = 0; i < 8; ++i)
        w1r[i] = reinterpret_cast<const float4*>(W1)[t + i * 256];
    #pragma unroll
    for (int i = 0; i < 8; ++i) {
        int w = (t + i * 256) * 4;
        int k = w >> 7, c = w & 127;
        *reinterpret_cast<float4*>(&wts[k * FHID + sw128(c)]) =
            reinterpret_cast<const float4*>(W0)[t + i * 256];
    }
    {
        int r = t >> 4, k0 = (t & 15) * 4;
        int grow = row0 + r;
        float4 a = make_float4(0, 0, 0, 0);
        if (grow < n)
            a = *reinterpret_cast<const float4*>(agg_io + (size_t)grow * FIN + k0);
        *reinterpret_cast<float4*>(&xs[r][k0]) = a;
    }
    __syncthreads();
    {
        int r0 = (t >> 5) * 2;
        int c0 = (t & 31) * 4;
        int c0s = sw128(c0);
        float4 bv = *reinterpret_cast<const float4*>(&b0[c0]);
        float acc[2][4];
        acc[0][0] = bv.x; acc[0][1] = bv.y; acc[0][2] = bv.z; acc[0][3] = bv.w;
        acc[1][0] = bv.x; acc[1][1] = bv.y; acc[1][2] = bv.z; acc[1][3] = bv.w;
        #pragma unroll 8
        for (int k = 0; k < FIN; ++k) {
            float4 w = *reinterpret_cast<const float4*>(&wts[k * FHID + c0s]);
            float x0 = xs[r0 + 0][k], x1 = xs[r0 + 1][k];
            acc[0][0] = fmaf(x0, w.x, acc[0][0]);
            acc[0][1] = fmaf(x0, w.y, acc[0][1]);
            acc[0][2] = fmaf(x0, w.z, acc[0][2]);
            acc[0][3] = fmaf(x0, w.w, acc[0][3]);
            acc[1][0] = fmaf(x1, w.x, acc[1][0]);
            acc[1][1] = fmaf(x1, w.y, acc[1][1]);
            acc[1][2] = fmaf(x1, w.z, acc[1][2]);
            acc[1][3] = fmaf(x1, w.w, acc[1][3]);
        }
        *reinterpret_cast<float4*>(&hs[r0 + 0][c0]) =
            make_float4(fmaxf(acc[0][0], 0.f), fmaxf(acc[0][1], 0.f),
                        fmaxf(acc[0][2], 0.f), fmaxf(acc[0][3], 0.f));
        *reinterpret_cast<float4*>(&hs[r0 + 1][c0]) =
            make_float4(fmaxf(acc[1][0], 0.f), fmaxf(acc[1][1], 0.f),
                        fmaxf(acc[1][2], 0.f), fmaxf(acc[1][3], 0.f));
    }
    __syncthreads();
    #pragma unroll
    for (int i = 0; i < 8; ++i)
        reinterpret_cast<float4*>(wts)[t + i * 256] = w1r[i];
    __syncthreads();
    {
        int r  = t >> 4;
        int c0 = (t & 15) * 4;
        float acc[4] = {0.f, 0.f, 0.f, 0.f};
        #pragma unroll 8
        for (int k = 0; k < FHID; ++k) {
            float4 w = *reinterpret_cast<const float4*>(&wts[k * FOUT + c0]);
            float h = hs[r][k];
            acc[0] = fmaf(h, w.x, acc[0]);
            acc[1] = fmaf(h, w.y, acc[1]);
            acc[2] = fmaf(h, w.z, acc[2]);
            acc[3] = fmaf(h, w.w, acc[3]);
        }
        int grow = row0 + r;
        if (grow < n)
            *reinterpret_cast<float4*>(&agg_io[(size_t)grow * FOUT + c0]) =
                make_float4(acc[0], acc[1], acc[2], acc[3]);
    }
}

extern "C" void kernel_launch(void* const* d_in, const int* in_sizes, int n_in,
                              void* d_out, int out_size, void* d_ws, size_t ws_size,
                              hipStream_t stream) {
    const float* x   = (const float*)d_in[0];
    const int*   ei  = (const int*)d_in[1];   // int32 [2, E]
    const float* W0  = (const float*)d_in[2];
    const float* b0  = (const float*)d_in[3];
    const float* W1  = (const float*)d_in[4];
    const float* b1  = (const float*)d_in[5];
    float*       out = (float*)d_out;

    const int n = in_sizes[0] / FIN;        // 100000
    const int e = in_sizes[1] / 2;          // 1600000
    const int* src = ei;
    const int* dst = ei + e;
    const int nb = (n + SCB - 1) / SCB;

    // common workspace prefix
    float* dis    = (float*)d_ws;                    // N
    float* buf    = dis + n;                         // N*64 fp32
    int*   counts = (int*)(buf + (size_t)n * FIN);   // N
    int*   rp     = counts + n;                      // N+1
    int*   bsums  = rp + (n + 1);                    // <=64
    int*   ssrc   = bsums + 64;                      // E
    char*  after  = (char*)(ssrc + e);

    // fp16 path: yh[N*64] half | hh[N*128] half (rank overlays hh)
    __half* yh = (__half*)after;
    __half* hh = yh + (size_t)n * FIN;
    size_t need16 = (size_t)((char*)(hh + (size_t)n * FHID) - (char*)d_ws);
    // fallback: rank[E] directly after ssrc
    size_t need_fb = (size_t)(after + (size_t)e * sizeof(int) - (char*)d_ws);

    if (ws_size >= need16) {
        int* rank = (int*)hh;               // dead before gemm1 writes hh
        hipMemsetAsync(counts, 0, (size_t)n * sizeof(int), stream);
        k_count<<<(e + 255) / 256, 256, 0, stream>>>(dst, counts, rank, e);
        k_scan1<<<nb, 256, 0, stream>>>(counts, rp, bsums, n);
        k_scan2<<<1, 64, 0, stream>>>(bsums, nb);
        k_scan3<<<(n + 255) / 256, 256, 0, stream>>>(rp, bsums, counts, dis, n, e);
        k_fill<<<(e + 255) / 256, 256, 0, stream>>>(src, dst, rp, rank, ssrc, e);

        // y1 = fp16(dis * x)
        k_toy<<<(n * 16 + 255) / 256, 256, 0, stream>>>(x, dis, yh, n);
        // layer 1: buf = dis[d]*(y1[d] + sum y1[s])
        k_pull16<<<(n + 3) / 4, 256, 0, stream>>>(rp, ssrc, dis, yh, b1, buf, n, 0);
        // MLP: hh = fp16(relu(buf@W0+b0)); yh = fp16(dis*(hh@W1))
        const int blocks = 2048, nwaves = blocks * 4;
        k_gemm1<<<blocks, 256, 0, stream>>>(buf, W0, b0, hh, n, nwaves);
        k_gemm2<<<blocks, 256, 0, stream>>>(hh, W1, dis, yh, n, nwaves);
        // layer 2: out = sigmoid(dis[d]*(y2[d] + sum y2[s]) + b1)
        k_pull16<<<(n + 3) / 4, 256, 0, stream>>>(rp, ssrc, dis, yh, b1, out, n, 1);
    } else if (ws_size >= need_fb) {
        int* rank = (int*)after;
        hipMemsetAsync(counts, 0, (size_t)n * sizeof(int), stream);
        k_count<<<(e + 255) / 256, 256, 0, stream>>>(dst, counts, rank, e);
        k_scan1<<<nb, 256, 0, stream>>>(counts, rp, bsums, n);
        k_scan2<<<1, 64, 0, stream>>>(bsums, nb);
        k_scan3<<<(n + 255) / 256, 256, 0, stream>>>(rp, bsums, counts, dis, n, e);
        k_fill<<<(e + 255) / 256, 256, 0, stream>>>(src, dst, rp, rank, ssrc, e);

        k_pull_agg<<<(n + 3) / 4, 256, 0, stream>>>(rp, ssrc, dis, x, b1, buf, n, 0);
        k_mlp_v3<<<(n + PR - 1) / PR, 256, 0, stream>>>(buf, W0, b0, W1, n);
        k_pull_agg<<<(n + 3) / 4, 256, 0, stream>>>(rp, ssrc, dis, buf, b1, out, n, 1);
    }
}